// Round 6
// baseline (402.668 us; speedup 1.0000x reference)
//
#include <hip/hip_runtime.h>
#include <hip/hip_bf16.h>
#include <math.h>

// MultiPerspectiveLayer: B=32, TL=TR=D=256, L=32
// out[b][t][0:32]=full, [32:64]=maxpool, [64:96]=attentive, [96:128]=max_attentive

typedef __attribute__((ext_vector_type(4)))  float f32x4;
typedef __attribute__((ext_vector_type(16))) float f32x16;
typedef __attribute__((ext_vector_type(8)))  short s16x8;   // 8 bf16 (4 VGPR) MFMA operand
typedef __attribute__((ext_vector_type(4)))  unsigned short u16x4;
typedef __attribute__((ext_vector_type(8)))  unsigned short u16x8;
typedef unsigned short u16;

#define DEV static __device__ __forceinline__

DEV u16 f2bf(float f) {                       // RNE float->bf16 (no NaN in data)
  unsigned u = __builtin_bit_cast(unsigned, f);
  return (u16)((u + 0x7FFFu + ((u >> 16) & 1u)) >> 16);
}
DEV float bf2f(u16 s) { return __builtin_bit_cast(float, ((unsigned)s) << 16); }
DEV f32x16 zero16() {
  f32x16 a;
  #pragma unroll
  for (int i = 0; i < 16; ++i) a[i] = 0.f;
  return a;
}

// ---------------- prep_lt: nl_inv[b*TL+i] = 1/sqrt(max(sum lt^2, eps)) --------
__global__ __launch_bounds__(256) void k_prep_lt(const float* __restrict__ lt,
                                                 float* __restrict__ nl_inv) {
  int w = threadIdx.x >> 6, lane = threadIdx.x & 63;
  int row = blockIdx.x * 4 + w;                       // 8192 rows
  f32x4 v = *(const f32x4*)(lt + (size_t)row * 256 + lane * 4);
  float s = v.x * v.x + v.y * v.y + v.z * v.z + v.w * v.w;
  #pragma unroll
  for (int m = 32; m >= 1; m >>= 1) s += __shfl_xor(s, m);
  if (lane == 0) nl_inv[row] = 1.0f / sqrtf(fmaxf(s, 1e-6f));
}

// ---------------- prep_rt: rt hi/lo bf16, transposed rtT (hi), nr_inv ---------
__global__ __launch_bounds__(256) void k_prep_rt(const float* __restrict__ rt,
                                                 u16* __restrict__ rt_hi,
                                                 u16* __restrict__ rt_lo,
                                                 u16* __restrict__ rtT,
                                                 float* __restrict__ nr_inv) {
  __shared__ u16 ldsT[256][68];                       // pad 68: conflict-spread transpose writes
  int b = blockIdx.x >> 2, j0 = (blockIdx.x & 3) * 64;
  int tid = threadIdx.x, w = tid >> 6, lane = tid & 63;
  for (int rep = 0; rep < 16; ++rep) {
    int jl = rep * 4 + w, j = j0 + jl;
    size_t base = ((size_t)b * 256 + j) * 256;
    float ss = 0.f;
    #pragma unroll
    for (int k = 0; k < 4; ++k) {
      int d = lane + k * 64;
      float f = rt[base + d];
      ss += f * f;
      u16 h = f2bf(f);
      rt_hi[base + d] = h;
      rt_lo[base + d] = f2bf(f - bf2f(h));
      ldsT[d][jl] = h;
    }
    #pragma unroll
    for (int m = 32; m >= 1; m >>= 1) ss += __shfl_xor(ss, m);
    if (lane == 0) nr_inv[b * 256 + j] = 1.0f / sqrtf(fmaxf(ss, 1e-6f));
  }
  __syncthreads();
  for (int rep = 0; rep < 16; ++rep) {                // write rtT[b][d][j0..j0+63]
    int c = rep * 256 + tid;
    int d = c >> 4, q = c & 15;
    u16x4 v = *(const u16x4*)&ldsT[d][q * 4];
    *(u16x4*)(rtT + ((size_t)b * 256 + d) * 256 + j0 + q * 4) = v;
  }
}

// ---------------- attentive path: scores (split-bf16 3-pass) + PV (2-pass) ----
// block = (b, 32-row i-tile); 4 waves; MFMA 16x16x32.
#define ATT_LTH 0
#define ATT_LTL 16384
#define ATT_RTH 32768
#define ATT_RTL 65536
#define ATT_RTT 98304
#define ATT_PH  131072
#define ATT_PL  135168
#define ATT_NLS 139264
#define ATT_NRS 139392
#define ATT_SM  140416

__global__ __launch_bounds__(256) void k_att(const float* __restrict__ lt,
                                             const u16* __restrict__ rt_hi,
                                             const u16* __restrict__ rt_lo,
                                             const u16* __restrict__ rtT,
                                             const float* __restrict__ nl_inv,
                                             const float* __restrict__ nr_inv,
                                             float* __restrict__ att) {
  extern __shared__ char sm[];
  char* LTH = sm + ATT_LTH;  char* LTL = sm + ATT_LTL;
  char* RTH = sm + ATT_RTH;  char* RTL = sm + ATT_RTL;
  char* RTT = sm + ATT_RTT;
  char* PH  = sm + ATT_PH;   char* PL  = sm + ATT_PL;
  float* nls = (float*)(sm + ATT_NLS);
  float* nrs = (float*)(sm + ATT_NRS);

  int b = blockIdx.x >> 3, i0 = (blockIdx.x & 7) * 32;
  int tid = threadIdx.x, w = tid >> 6, lane = tid & 63;

  // stage lt tile [32][256] -> hi/lo bf16, XOR-swizzled rows
  #pragma unroll
  for (int rep = 0; rep < 8; ++rep) {
    int c = rep * 256 + tid;
    int row = c >> 6, c4 = c & 63;
    f32x4 v = *(const f32x4*)(lt + ((size_t)b * 256 + i0 + row) * 256 + c4 * 4);
    u16x4 h, lo;
    #pragma unroll
    for (int k = 0; k < 4; ++k) { float f = v[k]; h[k] = f2bf(f); lo[k] = f2bf(f - bf2f(h[k])); }
    int off = row * 512 + ((c4 * 8) ^ ((row & 7) << 4));
    *(u16x4*)(LTH + off) = h;
    *(u16x4*)(LTL + off) = lo;
  }
  if (tid < 32) nls[tid] = nl_inv[b * 256 + i0 + tid];
  nrs[tid] = nr_inv[b * 256 + tid];

  int ih = w >> 1;
  f32x4 accv[8];
  #pragma unroll
  for (int i = 0; i < 8; ++i) { accv[i].x = 0; accv[i].y = 0; accv[i].z = 0; accv[i].w = 0; }

  for (int jt = 0; jt < 4; ++jt) {
    int j0 = jt * 64;
    __syncthreads();                                   // protect rt/rtT/P from prev iter readers
    #pragma unroll
    for (int rep = 0; rep < 8; ++rep) {                // rt j-tile [64][256] hi/lo
      int c = rep * 256 + tid;
      int row = c >> 5, s = c & 31;
      size_t g = ((size_t)b * 256 + j0 + row) * 256 + s * 8;
      int off = row * 512 + ((s * 16) ^ ((row & 7) << 4));
      *(u16x8*)(RTH + off) = *(const u16x8*)(rt_hi + g);
      *(u16x8*)(RTL + off) = *(const u16x8*)(rt_lo + g);
    }
    #pragma unroll
    for (int rep = 0; rep < 8; ++rep) {                // rtT tile [256][64] (hi)
      int c = rep * 256 + tid;
      int d = c >> 3, s = c & 7;
      *(u16x8*)(RTT + d * 128 + ((s * 16) ^ ((d & 7) << 4))) =
          *(const u16x8*)(rtT + ((size_t)b * 256 + d) * 256 + j0 + s * 8);
    }
    __syncthreads();

    // QK^T: S[32][64]; wave w does frags (ih, jqs..jqs+1); 3-pass split
    f32x4 S[2];
    #pragma unroll
    for (int t = 0; t < 2; ++t) { S[t].x = 0; S[t].y = 0; S[t].z = 0; S[t].w = 0; }
    int jqs = (w & 1) * 2;
    #pragma unroll
    for (int ks = 0; ks < 8; ++ks) {
      int k2 = (ks * 32 + (lane >> 4) * 8) * 2;
      int ar = ih * 16 + (lane & 15);
      int ab = ar * 512 + (k2 ^ ((ar & 7) << 4));
      s16x8 ah = *(const s16x8*)(LTH + ab);
      s16x8 al = *(const s16x8*)(LTL + ab);
      #pragma unroll
      for (int fj = 0; fj < 2; ++fj) {
        int br = (jqs + fj) * 16 + (lane & 15);
        int bb = br * 512 + (k2 ^ ((br & 7) << 4));
        s16x8 bh = *(const s16x8*)(RTH + bb);
        s16x8 bl = *(const s16x8*)(RTL + bb);
        S[fj] = __builtin_amdgcn_mfma_f32_16x16x32_bf16(ah, bh, S[fj], 0, 0, 0);
        S[fj] = __builtin_amdgcn_mfma_f32_16x16x32_bf16(ah, bl, S[fj], 0, 0, 0);
        S[fj] = __builtin_amdgcn_mfma_f32_16x16x32_bf16(al, bh, S[fj], 0, 0, 0);
      }
    }
    // scale by 1/(nl*nr), split to P_hi/P_lo
    #pragma unroll
    for (int fj = 0; fj < 2; ++fj) {
      #pragma unroll
      for (int r = 0; r < 4; ++r) {
        int i = ih * 16 + (lane >> 4) * 4 + r;
        int j = (jqs + fj) * 16 + (lane & 15);
        float v = S[fj][r] * nls[i] * nrs[j0 + j];
        u16 h = f2bf(v), l2 = f2bf(v - bf2f(h));
        int pb = i * 128 + ((j * 2) ^ ((i & 7) << 4));
        *(u16*)(PH + pb) = h;
        *(u16*)(PL + pb) = l2;
      }
    }
    __syncthreads();

    // PV: att[32][256] += P @ rt ; B-operand from rtT (contiguous j); 2-pass split on P
    int db = (w & 1) * 128;
    #pragma unroll
    for (int ks = 0; ks < 2; ++ks) {
      int k2 = (ks * 32 + (lane >> 4) * 8) * 2;
      int pr = ih * 16 + (lane & 15);
      int pb = pr * 128 + (k2 ^ ((pr & 7) << 4));
      s16x8 ph = *(const s16x8*)(PH + pb);
      s16x8 pl = *(const s16x8*)(PL + pb);
      #pragma unroll
      for (int dq = 0; dq < 8; ++dq) {
        int dr = db + dq * 16 + (lane & 15);
        int bb = dr * 128 + (k2 ^ ((dr & 7) << 4));
        s16x8 bv = *(const s16x8*)(RTT + bb);
        accv[dq] = __builtin_amdgcn_mfma_f32_16x16x32_bf16(ph, bv, accv[dq], 0, 0, 0);
        accv[dq] = __builtin_amdgcn_mfma_f32_16x16x32_bf16(pl, bv, accv[dq], 0, 0, 0);
      }
    }
  }
  // epilogue: write att fp32
  #pragma unroll
  for (int dq = 0; dq < 8; ++dq) {
    #pragma unroll
    for (int r = 0; r < 4; ++r) {
      int i = i0 + ih * 16 + (lane >> 4) * 4 + r;
      int d = (w & 1) * 128 + dq * 16 + (lane & 15);
      att[((size_t)b * 256 + i) * 256 + d] = accv[dq][r];
    }
  }
}

// ---------------- maxpool matching: A-in-registers, B in LDS ------------------
// block = (b, l, i0 in {0,128}); 4 waves: wave (wi,wj) owns 64i x 64j per jt.
// LDS: Bm [128][256] bf16 swizzled (64 KB) + wrow (1 KB) + red[4][128] (2 KB)
//  => 67.5 KB => 2 blocks/CU. A (lt*W[l], 64 rows x K=256) lives in 128 VGPRs.
#define MP_B   0
#define MP_W   65536
#define MP_RED 66560
#define MP_SM  68608

__global__ __launch_bounds__(256, 2) void k_maxpool(const float* __restrict__ lt,
                                                    const u16* __restrict__ rt_hi,
                                                    const float* __restrict__ Wmp,
                                                    float* __restrict__ out) {
  extern __shared__ char sm[];
  char* Bm = sm + MP_B;
  float* wrow = (float*)(sm + MP_W);
  float* red = (float*)(sm + MP_RED);

  int b = blockIdx.x >> 6, rem = blockIdx.x & 63;
  int l = rem >> 1, i0 = (rem & 1) * 128;
  int tid = threadIdx.x, w = tid >> 6, lane = tid & 63;
  int wi = w >> 1, wj = w & 1;

  wrow[tid] = Wmp[l * 256 + tid];
  __syncthreads();

  // A in regs: rows i0 + wi*64 + rb*32 + (lane&31), cols ks*16 + (lane>>5)*8 + 0..7
  s16x8 areg[2][16];
  {
    int kc0 = (lane >> 5) * 8;
    #pragma unroll
    for (int rb = 0; rb < 2; ++rb) {
      int row = i0 + wi * 64 + rb * 32 + (lane & 31);
      const float* src = lt + ((size_t)b * 256 + row) * 256 + kc0;
      #pragma unroll
      for (int ks = 0; ks < 16; ++ks) {
        f32x4 v0 = *(const f32x4*)(src + ks * 16);
        f32x4 v1 = *(const f32x4*)(src + ks * 16 + 4);
        f32x4 w0 = *(const f32x4*)(wrow + kc0 + ks * 16);
        f32x4 w1 = *(const f32x4*)(wrow + kc0 + ks * 16 + 4);
        s16x8 a;
        a[0] = (short)f2bf(v0.x * w0.x); a[1] = (short)f2bf(v0.y * w0.y);
        a[2] = (short)f2bf(v0.z * w0.z); a[3] = (short)f2bf(v0.w * w0.w);
        a[4] = (short)f2bf(v1.x * w1.x); a[5] = (short)f2bf(v1.y * w1.y);
        a[6] = (short)f2bf(v1.z * w1.z); a[7] = (short)f2bf(v1.w * w1.w);
        areg[rb][ks] = a;
      }
    }
  }

  for (int jt = 0; jt < 2; ++jt) {
    __syncthreads();                                   // Bm free (prev readers done)
    #pragma unroll
    for (int rep = 0; rep < 16; ++rep) {               // stage B j-tile [128][256]
      int c = rep * 256 + tid;
      int row = c >> 5, s = c & 31;
      *(u16x8*)(Bm + row * 512 + ((s * 16) ^ ((row & 7) << 4))) =
          *(const u16x8*)(rt_hi + ((size_t)b * 256 + jt * 128 + row) * 256 + s * 8);
    }
    __syncthreads();

    f32x16 a00 = zero16(), a01 = zero16(), a10 = zero16(), a11 = zero16();
    int jl0 = wj * 64 + (lane & 31), jl1 = jl0 + 32;
    #pragma unroll
    for (int ks = 0; ks < 16; ++ks) {
      int k2 = (ks * 16 + (lane >> 5) * 8) * 2;
      s16x8 fb0 = *(const s16x8*)(Bm + jl0 * 512 + (k2 ^ ((jl0 & 7) << 4)));
      s16x8 fb1 = *(const s16x8*)(Bm + jl1 * 512 + (k2 ^ ((jl1 & 7) << 4)));
      a00 = __builtin_amdgcn_mfma_f32_32x32x16_bf16(areg[0][ks], fb0, a00, 0, 0, 0);
      a01 = __builtin_amdgcn_mfma_f32_32x32x16_bf16(areg[0][ks], fb1, a01, 0, 0, 0);
      a10 = __builtin_amdgcn_mfma_f32_32x32x16_bf16(areg[1][ks], fb0, a10, 0, 0, 0);
      a11 = __builtin_amdgcn_mfma_f32_32x32x16_bf16(areg[1][ks], fb1, a11, 0, 0, 0);
    }
    // rowmax over this jt's 64 j's: fmax over b-frags, then over 32 lanes (j)
    #pragma unroll
    for (int rb = 0; rb < 2; ++rb) {
      #pragma unroll
      for (int r = 0; r < 16; ++r) {
        float v = (rb == 0) ? fmaxf(a00[r], a01[r]) : fmaxf(a10[r], a11[r]);
        #pragma unroll
        for (int m = 16; m >= 1; m >>= 1) v = fmaxf(v, __shfl_xor(v, m));
        if ((lane & 31) == 0)
          red[(jt * 2 + wj) * 128 + wi * 64 + rb * 32 +
              (r & 3) + 8 * (r >> 2) + 4 * (lane >> 5)] = v;
      }
    }
  }
  __syncthreads();
  if (tid < 128) {
    float m = fmaxf(fmaxf(red[tid], red[128 + tid]),
                    fmaxf(red[256 + tid], red[384 + tid]));
    out[((size_t)b * 256 + i0 + tid) * 128 + 32 + l] = tanhf(m);
  }
}

// ---------------- finals: full / attentive / max_attentive (exact fp32) ------
// W matrices read straight from global (L1/L2-resident, 96 KB total) — LDS only
// for u/v/hr (17.4 KB) so occupancy is no longer LDS-capped.
#define FN_U  0
#define FN_V  8320
#define FN_HR 16640
#define FN_SM 17664

__global__ __launch_bounds__(256) void k_finals(const float* __restrict__ lt,
                                                const float* __restrict__ fh,
                                                const float* __restrict__ bh,
                                                const float* __restrict__ Wf,
                                                const float* __restrict__ Wa,
                                                const float* __restrict__ Wm,
                                                const float* __restrict__ attw,
                                                float* __restrict__ out) {
  extern __shared__ char sm[];
  float* u  = (float*)(sm + FN_U);                    // [8][260]
  float* v  = (float*)(sm + FN_V);
  float* hr = (float*)(sm + FN_HR);                   // [256]

  int b = blockIdx.x >> 5, r0 = (blockIdx.x & 31) * 8;
  int tid = threadIdx.x;

  if (tid < 64) {                                     // h_rt = concat(fh, bh)
    int k = tid * 4;
    f32x4 x = (tid < 32) ? *(const f32x4*)(fh + b * 128 + k)
                         : *(const f32x4*)(bh + b * 128 + k - 128);
    *(f32x4*)(hr + k) = x;
  }
  __syncthreads();
  #pragma unroll
  for (int rep = 0; rep < 2; ++rep) {                 // u = lt*h_rt ; v = lt*att
    int c = rep * 256 + tid;
    int row = c >> 6, c4 = c & 63;
    size_t g = ((size_t)b * 256 + r0 + row) * 256 + c4 * 4;
    f32x4 lv = *(const f32x4*)(lt + g);
    f32x4 hv = *(const f32x4*)(hr + c4 * 4);
    f32x4 av = *(const f32x4*)(attw + g);
    *(f32x4*)(u + row * 260 + c4 * 4) = lv * hv;
    *(f32x4*)(v + row * 260 + c4 * 4) = lv * av;
  }
  __syncthreads();
  int r = tid >> 5, l = tid & 31;
  float af = 0.f, aa = 0.f, am = 0.f;
  #pragma unroll 8
  for (int c4 = 0; c4 < 64; ++c4) {
    f32x4 uu = *(const f32x4*)(u + r * 260 + c4 * 4);
    f32x4 vv = *(const f32x4*)(v + r * 260 + c4 * 4);
    f32x4 w1 = *(const f32x4*)(Wf + l * 256 + c4 * 4);
    f32x4 w2 = *(const f32x4*)(Wa + l * 256 + c4 * 4);
    f32x4 w3 = *(const f32x4*)(Wm + l * 256 + c4 * 4);
    af += uu.x * w1.x + uu.y * w1.y + uu.z * w1.z + uu.w * w1.w;
    aa += vv.x * w2.x + vv.y * w2.y + vv.z * w2.z + vv.w * w2.w;
    am += vv.x * w3.x + vv.y * w3.y + vv.z * w3.z + vv.w * w3.w;
  }
  size_t ob = ((size_t)b * 256 + r0 + r) * 128;
  out[ob + l]      = tanhf(af);
  out[ob + 64 + l] = tanhf(aa);
  out[ob + 96 + l] = tanhf(am);
}

// ---------------- launch ------------------------------------------------------
extern "C" void kernel_launch(void* const* d_in, const int* in_sizes, int n_in,
                              void* d_out, int out_size, void* d_ws, size_t ws_size,
                              hipStream_t stream) {
  const float* lt  = (const float*)d_in[0];
  const float* rt  = (const float*)d_in[5];
  const float* fh  = (const float*)d_in[6];
  const float* bh  = (const float*)d_in[8];
  const float* Wf  = (const float*)d_in[10];
  const float* Wmp = (const float*)d_in[11];
  const float* Wa  = (const float*)d_in[12];
  const float* Wm  = (const float*)d_in[13];
  float* out = (float*)d_out;

  char* ws = (char*)d_ws;
  u16* rt_hi = (u16*)(ws);                      // 4 MB
  u16* rt_lo = (u16*)(ws + (4u << 20));         // 4 MB
  u16* rtT   = (u16*)(ws + (8u << 20));         // 4 MB
  float* att = (float*)(ws + (12u << 20));      // 8 MB
  float* nl_inv = (float*)(ws + (20u << 20));
  float* nr_inv = (float*)(ws + (20u << 20) + 32768);

  (void)hipFuncSetAttribute((const void*)k_att,     hipFuncAttributeMaxDynamicSharedMemorySize, ATT_SM);
  (void)hipFuncSetAttribute((const void*)k_maxpool, hipFuncAttributeMaxDynamicSharedMemorySize, MP_SM);
  (void)hipFuncSetAttribute((const void*)k_finals,  hipFuncAttributeMaxDynamicSharedMemorySize, FN_SM);

  k_prep_lt<<<2048, 256, 0, stream>>>(lt, nl_inv);
  k_prep_rt<<<128, 256, 0, stream>>>(rt, rt_hi, rt_lo, rtT, nr_inv);
  k_att<<<256, 256, ATT_SM, stream>>>(lt, rt_hi, rt_lo, rtT, nl_inv, nr_inv, att);
  k_maxpool<<<2048, 256, MP_SM, stream>>>(lt, rt_hi, Wmp, out);
  k_finals<<<1024, 256, FN_SM, stream>>>(lt, fh, bh, Wf, Wa, Wm, att, out);
}

// Round 11
// 308.612 us; speedup vs baseline: 1.3048x; 1.3048x over previous
//
#include <hip/hip_runtime.h>
#include <hip/hip_bf16.h>
#include <math.h>

// MultiPerspectiveLayer: B=32, TL=TR=D=256, L=32
// out[b][t][0:32]=full, [32:64]=maxpool, [64:96]=attentive, [96:128]=max_attentive

typedef __attribute__((ext_vector_type(4)))  float f32x4;
typedef __attribute__((ext_vector_type(16))) float f32x16;
typedef __attribute__((ext_vector_type(8)))  short s16x8;   // 8 bf16 (4 VGPR) MFMA operand
typedef __attribute__((ext_vector_type(4)))  unsigned short u16x4;
typedef __attribute__((ext_vector_type(8)))  unsigned short u16x8;
typedef unsigned short u16;

#define DEV static __device__ __forceinline__

DEV u16 f2bf(float f) {                       // RNE float->bf16 (no NaN in data)
  unsigned u = __builtin_bit_cast(unsigned, f);
  return (u16)((u + 0x7FFFu + ((u >> 16) & 1u)) >> 16);
}
DEV float bf2f(u16 s) { return __builtin_bit_cast(float, ((unsigned)s) << 16); }
DEV f32x16 zero16() {
  f32x16 a;
  #pragma unroll
  for (int i = 0; i < 16; ++i) a[i] = 0.f;
  return a;
}

// ---------------- prep_lt: nl_inv[b*TL+i] = 1/sqrt(max(sum lt^2, eps)) --------
__global__ __launch_bounds__(256) void k_prep_lt(const float* __restrict__ lt,
                                                 float* __restrict__ nl_inv) {
  int w = threadIdx.x >> 6, lane = threadIdx.x & 63;
  int row = blockIdx.x * 4 + w;                       // 8192 rows
  f32x4 v = *(const f32x4*)(lt + (size_t)row * 256 + lane * 4);
  float s = v.x * v.x + v.y * v.y + v.z * v.z + v.w * v.w;
  #pragma unroll
  for (int m = 32; m >= 1; m >>= 1) s += __shfl_xor(s, m);
  if (lane == 0) nl_inv[row] = 1.0f / sqrtf(fmaxf(s, 1e-6f));
}

// ---------------- prep_rt: rt hi/lo bf16, transposed rtT (hi), nr_inv ---------
__global__ __launch_bounds__(256) void k_prep_rt(const float* __restrict__ rt,
                                                 u16* __restrict__ rt_hi,
                                                 u16* __restrict__ rt_lo,
                                                 u16* __restrict__ rtT,
                                                 float* __restrict__ nr_inv) {
  __shared__ u16 ldsT[256][68];                       // pad 68: conflict-spread transpose writes
  int b = blockIdx.x >> 2, j0 = (blockIdx.x & 3) * 64;
  int tid = threadIdx.x, w = tid >> 6, lane = tid & 63;
  for (int rep = 0; rep < 16; ++rep) {
    int jl = rep * 4 + w, j = j0 + jl;
    size_t base = ((size_t)b * 256 + j) * 256;
    float ss = 0.f;
    #pragma unroll
    for (int k = 0; k < 4; ++k) {
      int d = lane + k * 64;
      float f = rt[base + d];
      ss += f * f;
      u16 h = f2bf(f);
      rt_hi[base + d] = h;
      rt_lo[base + d] = f2bf(f - bf2f(h));
      ldsT[d][jl] = h;
    }
    #pragma unroll
    for (int m = 32; m >= 1; m >>= 1) ss += __shfl_xor(ss, m);
    if (lane == 0) nr_inv[b * 256 + j] = 1.0f / sqrtf(fmaxf(ss, 1e-6f));
  }
  __syncthreads();
  for (int rep = 0; rep < 16; ++rep) {                // write rtT[b][d][j0..j0+63]
    int c = rep * 256 + tid;
    int d = c >> 4, q = c & 15;
    u16x4 v = *(const u16x4*)&ldsT[d][q * 4];
    *(u16x4*)(rtT + ((size_t)b * 256 + d) * 256 + j0 + q * 4) = v;
  }
}

// ---------------- attentive path: scores (split-bf16 3-pass) + PV (2-pass) ----
// block = (b, 32-row i-tile); 4 waves; MFMA 16x16x32.
#define ATT_LTH 0
#define ATT_LTL 16384
#define ATT_RTH 32768
#define ATT_RTL 65536
#define ATT_RTT 98304
#define ATT_PH  131072
#define ATT_PL  135168
#define ATT_NLS 139264
#define ATT_NRS 139392
#define ATT_SM  140416

__global__ __launch_bounds__(256) void k_att(const float* __restrict__ lt,
                                             const u16* __restrict__ rt_hi,
                                             const u16* __restrict__ rt_lo,
                                             const u16* __restrict__ rtT,
                                             const float* __restrict__ nl_inv,
                                             const float* __restrict__ nr_inv,
                                             float* __restrict__ att) {
  extern __shared__ char sm[];
  char* LTH = sm + ATT_LTH;  char* LTL = sm + ATT_LTL;
  char* RTH = sm + ATT_RTH;  char* RTL = sm + ATT_RTL;
  char* RTT = sm + ATT_RTT;
  char* PH  = sm + ATT_PH;   char* PL  = sm + ATT_PL;
  float* nls = (float*)(sm + ATT_NLS);
  float* nrs = (float*)(sm + ATT_NRS);

  int b = blockIdx.x >> 3, i0 = (blockIdx.x & 7) * 32;
  int tid = threadIdx.x, w = tid >> 6, lane = tid & 63;

  // stage lt tile [32][256] -> hi/lo bf16, XOR-swizzled rows
  #pragma unroll
  for (int rep = 0; rep < 8; ++rep) {
    int c = rep * 256 + tid;
    int row = c >> 6, c4 = c & 63;
    f32x4 v = *(const f32x4*)(lt + ((size_t)b * 256 + i0 + row) * 256 + c4 * 4);
    u16x4 h, lo;
    #pragma unroll
    for (int k = 0; k < 4; ++k) { float f = v[k]; h[k] = f2bf(f); lo[k] = f2bf(f - bf2f(h[k])); }
    int off = row * 512 + ((c4 * 8) ^ ((row & 7) << 4));
    *(u16x4*)(LTH + off) = h;
    *(u16x4*)(LTL + off) = lo;
  }
  if (tid < 32) nls[tid] = nl_inv[b * 256 + i0 + tid];
  nrs[tid] = nr_inv[b * 256 + tid];

  int ih = w >> 1;
  f32x4 accv[8];
  #pragma unroll
  for (int i = 0; i < 8; ++i) { accv[i].x = 0; accv[i].y = 0; accv[i].z = 0; accv[i].w = 0; }

  for (int jt = 0; jt < 4; ++jt) {
    int j0 = jt * 64;
    __syncthreads();                                   // protect rt/rtT/P from prev iter readers
    #pragma unroll
    for (int rep = 0; rep < 8; ++rep) {                // rt j-tile [64][256] hi/lo
      int c = rep * 256 + tid;
      int row = c >> 5, s = c & 31;
      size_t g = ((size_t)b * 256 + j0 + row) * 256 + s * 8;
      int off = row * 512 + ((s * 16) ^ ((row & 7) << 4));
      *(u16x8*)(RTH + off) = *(const u16x8*)(rt_hi + g);
      *(u16x8*)(RTL + off) = *(const u16x8*)(rt_lo + g);
    }
    #pragma unroll
    for (int rep = 0; rep < 8; ++rep) {                // rtT tile [256][64] (hi)
      int c = rep * 256 + tid;
      int d = c >> 3, s = c & 7;
      *(u16x8*)(RTT + d * 128 + ((s * 16) ^ ((d & 7) << 4))) =
          *(const u16x8*)(rtT + ((size_t)b * 256 + d) * 256 + j0 + s * 8);
    }
    __syncthreads();

    // QK^T: S[32][64]; wave w does frags (ih, jqs..jqs+1); 3-pass split
    f32x4 S[2];
    #pragma unroll
    for (int t = 0; t < 2; ++t) { S[t].x = 0; S[t].y = 0; S[t].z = 0; S[t].w = 0; }
    int jqs = (w & 1) * 2;
    #pragma unroll
    for (int ks = 0; ks < 8; ++ks) {
      int k2 = (ks * 32 + (lane >> 4) * 8) * 2;
      int ar = ih * 16 + (lane & 15);
      int ab = ar * 512 + (k2 ^ ((ar & 7) << 4));
      s16x8 ah = *(const s16x8*)(LTH + ab);
      s16x8 al = *(const s16x8*)(LTL + ab);
      #pragma unroll
      for (int fj = 0; fj < 2; ++fj) {
        int br = (jqs + fj) * 16 + (lane & 15);
        int bb = br * 512 + (k2 ^ ((br & 7) << 4));
        s16x8 bh = *(const s16x8*)(RTH + bb);
        s16x8 bl = *(const s16x8*)(RTL + bb);
        S[fj] = __builtin_amdgcn_mfma_f32_16x16x32_bf16(ah, bh, S[fj], 0, 0, 0);
        S[fj] = __builtin_amdgcn_mfma_f32_16x16x32_bf16(ah, bl, S[fj], 0, 0, 0);
        S[fj] = __builtin_amdgcn_mfma_f32_16x16x32_bf16(al, bh, S[fj], 0, 0, 0);
      }
    }
    // scale by 1/(nl*nr), split to P_hi/P_lo
    #pragma unroll
    for (int fj = 0; fj < 2; ++fj) {
      #pragma unroll
      for (int r = 0; r < 4; ++r) {
        int i = ih * 16 + (lane >> 4) * 4 + r;
        int j = (jqs + fj) * 16 + (lane & 15);
        float v = S[fj][r] * nls[i] * nrs[j0 + j];
        u16 h = f2bf(v), l2 = f2bf(v - bf2f(h));
        int pb = i * 128 + ((j * 2) ^ ((i & 7) << 4));
        *(u16*)(PH + pb) = h;
        *(u16*)(PL + pb) = l2;
      }
    }
    __syncthreads();

    // PV: att[32][256] += P @ rt ; B-operand from rtT (contiguous j); 2-pass split on P
    int db = (w & 1) * 128;
    #pragma unroll
    for (int ks = 0; ks < 2; ++ks) {
      int k2 = (ks * 32 + (lane >> 4) * 8) * 2;
      int pr = ih * 16 + (lane & 15);
      int pb = pr * 128 + (k2 ^ ((pr & 7) << 4));
      s16x8 ph = *(const s16x8*)(PH + pb);
      s16x8 pl = *(const s16x8*)(PL + pb);
      #pragma unroll
      for (int dq = 0; dq < 8; ++dq) {
        int dr = db + dq * 16 + (lane & 15);
        int bb = dr * 128 + (k2 ^ ((dr & 7) << 4));
        s16x8 bv = *(const s16x8*)(RTT + bb);
        accv[dq] = __builtin_amdgcn_mfma_f32_16x16x32_bf16(ph, bv, accv[dq], 0, 0, 0);
        accv[dq] = __builtin_amdgcn_mfma_f32_16x16x32_bf16(pl, bv, accv[dq], 0, 0, 0);
      }
    }
  }
  // epilogue: write att fp32
  #pragma unroll
  for (int dq = 0; dq < 8; ++dq) {
    #pragma unroll
    for (int r = 0; r < 4; ++r) {
      int i = i0 + ih * 16 + (lane >> 4) * 4 + r;
      int d = (w & 1) * 128 + dq * 16 + (lane & 15);
      att[((size_t)b * 256 + i) * 256 + d] = accv[dq][r];
    }
  }
}

// ---------------- maxpool matching v3: K-split staged tiles -------------------
// block = (b, l, i0 in {0,128}); 4 waves (wi,wj), wave tile 64i x 64j (2x2 frags,
// 1:1 ds_read:MFMA). LDS: A[128i][128k] bf16 swz (32 KB) + B[128j][128k] (32 KB)
// + red[2][128] (1 KB) = 65.5 KB -> 2 blocks/CU. acc[2][4] f32x16 persists over
// the 2 K-half stages; fa frags cached in regs per kt and reused for both jt.
#define MP_A   0
#define MP_B   32768
#define MP_RED 65536
#define MP_SM  66560

__global__ __launch_bounds__(256, 2) void k_maxpool(const float* __restrict__ lt,
                                                    const u16* __restrict__ rt_hi,
                                                    const float* __restrict__ Wmp,
                                                    float* __restrict__ out) {
  extern __shared__ char sm[];
  char* A  = sm + MP_A;
  char* Bm = sm + MP_B;
  float* red = (float*)(sm + MP_RED);                 // [2 wj][128 i]

  int b = blockIdx.x >> 6, rem = blockIdx.x & 63;
  int l = rem >> 1, i0 = (rem & 1) * 128;
  int tid = threadIdx.x, lane = tid & 63;
  int w = tid >> 6, wi = w >> 1, wj = w & 1;
  int s = tid & 15;                                   // k-slot (rep-invariant)

  f32x16 acc[2][4];                                   // [jt][fi*2+fj]
  #pragma unroll
  for (int jt = 0; jt < 2; ++jt) {
    #pragma unroll
    for (int q = 0; q < 4; ++q) acc[jt][q] = zero16();
  }

  #pragma unroll
  for (int kt = 0; kt < 2; ++kt) {
    __syncthreads();                                  // A/B free from prev stage readers
    // per-thread W slice (8 fp32) for this k-half
    f32x4 w0 = *(const f32x4*)(Wmp + l * 256 + kt * 128 + s * 8);
    f32x4 w1 = *(const f32x4*)(Wmp + l * 256 + kt * 128 + s * 8 + 4);
    // stage A = bf16(lt * W[l])  [128 i][128 k], swizzled
    #pragma unroll
    for (int rep = 0; rep < 8; ++rep) {
      int row = rep * 16 + (tid >> 4);
      const float* src = lt + ((size_t)b * 256 + i0 + row) * 256 + kt * 128 + s * 8;
      f32x4 v0 = *(const f32x4*)src, v1 = *(const f32x4*)(src + 4);
      u16x8 hv;
      hv[0] = f2bf(v0.x * w0.x); hv[1] = f2bf(v0.y * w0.y);
      hv[2] = f2bf(v0.z * w0.z); hv[3] = f2bf(v0.w * w0.w);
      hv[4] = f2bf(v1.x * w1.x); hv[5] = f2bf(v1.y * w1.y);
      hv[6] = f2bf(v1.z * w1.z); hv[7] = f2bf(v1.w * w1.w);
      *(u16x8*)(A + row * 256 + ((s * 16) ^ ((row & 7) << 4))) = hv;
    }
    // stage B = rt_hi j-tile 0  [128 j][128 k], swizzled
    #pragma unroll
    for (int rep = 0; rep < 8; ++rep) {
      int row = rep * 16 + (tid >> 4);
      *(u16x8*)(Bm + row * 256 + ((s * 16) ^ ((row & 7) << 4))) =
          *(const u16x8*)(rt_hi + ((size_t)b * 256 + row) * 256 + kt * 128 + s * 8);
    }
    __syncthreads();

    // A-frags to regs (reused for both jt)
    s16x8 fa[2][8];
    #pragma unroll
    for (int ks = 0; ks < 8; ++ks) {
      int k2 = (ks * 16 + (lane >> 5) * 8) * 2;
      #pragma unroll
      for (int fi = 0; fi < 2; ++fi) {
        int r = wi * 64 + fi * 32 + (lane & 31);
        fa[fi][ks] = *(const s16x8*)(A + r * 256 + (k2 ^ ((r & 7) << 4)));
      }
    }
    // MFMA jt=0
    #pragma unroll
    for (int ks = 0; ks < 8; ++ks) {
      int k2 = (ks * 16 + (lane >> 5) * 8) * 2;
      int r0 = wj * 64 + (lane & 31), r1 = r0 + 32;
      s16x8 fb0 = *(const s16x8*)(Bm + r0 * 256 + (k2 ^ ((r0 & 7) << 4)));
      s16x8 fb1 = *(const s16x8*)(Bm + r1 * 256 + (k2 ^ ((r1 & 7) << 4)));
      acc[0][0] = __builtin_amdgcn_mfma_f32_32x32x16_bf16(fa[0][ks], fb0, acc[0][0], 0, 0, 0);
      acc[0][1] = __builtin_amdgcn_mfma_f32_32x32x16_bf16(fa[0][ks], fb1, acc[0][1], 0, 0, 0);
      acc[0][2] = __builtin_amdgcn_mfma_f32_32x32x16_bf16(fa[1][ks], fb0, acc[0][2], 0, 0, 0);
      acc[0][3] = __builtin_amdgcn_mfma_f32_32x32x16_bf16(fa[1][ks], fb1, acc[0][3], 0, 0, 0);
    }
    __syncthreads();                                  // B(jt=0) readers done
    // stage B = rt_hi j-tile 1
    #pragma unroll
    for (int rep = 0; rep < 8; ++rep) {
      int row = rep * 16 + (tid >> 4);
      *(u16x8*)(Bm + row * 256 + ((s * 16) ^ ((row & 7) << 4))) =
          *(const u16x8*)(rt_hi + ((size_t)b * 256 + 128 + row) * 256 + kt * 128 + s * 8);
    }
    __syncthreads();
    // MFMA jt=1 (reuse fa)
    #pragma unroll
    for (int ks = 0; ks < 8; ++ks) {
      int k2 = (ks * 16 + (lane >> 5) * 8) * 2;
      int r0 = wj * 64 + (lane & 31), r1 = r0 + 32;
      s16x8 fb0 = *(const s16x8*)(Bm + r0 * 256 + (k2 ^ ((r0 & 7) << 4)));
      s16x8 fb1 = *(const s16x8*)(Bm + r1 * 256 + (k2 ^ ((r1 & 7) << 4)));
      acc[1][0] = __builtin_amdgcn_mfma_f32_32x32x16_bf16(fa[0][ks], fb0, acc[1][0], 0, 0, 0);
      acc[1][1] = __builtin_amdgcn_mfma_f32_32x32x16_bf16(fa[0][ks], fb1, acc[1][1], 0, 0, 0);
      acc[1][2] = __builtin_amdgcn_mfma_f32_32x32x16_bf16(fa[1][ks], fb0, acc[1][2], 0, 0, 0);
      acc[1][3] = __builtin_amdgcn_mfma_f32_32x32x16_bf16(fa[1][ks], fb1, acc[1][3], 0, 0, 0);
    }
  }

  // rowmax: over fj frags + both jt (regs), then 32 lanes (j), per-wj partials
  #pragma unroll
  for (int fi = 0; fi < 2; ++fi) {
    #pragma unroll
    for (int r = 0; r < 16; ++r) {
      float v = fmaxf(fmaxf(acc[0][fi * 2][r], acc[0][fi * 2 + 1][r]),
                      fmaxf(acc[1][fi * 2][r], acc[1][fi * 2 + 1][r]));
      #pragma unroll
      for (int m = 16; m >= 1; m >>= 1) v = fmaxf(v, __shfl_xor(v, m));
      if ((lane & 31) == 0)
        red[wj * 128 + wi * 64 + fi * 32 + (r & 3) + 8 * (r >> 2) + 4 * (lane >> 5)] = v;
    }
  }
  __syncthreads();
  if (tid < 128) {
    float m = fmaxf(red[tid], red[128 + tid]);
    out[((size_t)b * 256 + i0 + tid) * 128 + 32 + l] = tanhf(m);
  }
}

// ---------------- finals: full / attentive / max_attentive (exact fp32) ------
// W matrices read straight from global (L1/L2-resident, 96 KB total) — LDS only
// for u/v/hr (17.4 KB) so occupancy is no longer LDS-capped.
#define FN_U  0
#define FN_V  8320
#define FN_HR 16640
#define FN_SM 17664

__global__ __launch_bounds__(256) void k_finals(const float* __restrict__ lt,
                                                const float* __restrict__ fh,
                                                const float* __restrict__ bh,
                                                const float* __restrict__ Wf,
                                                const float* __restrict__ Wa,
                                                const float* __restrict__ Wm,
                                                const float* __restrict__ attw,
                                                float* __restrict__ out) {
  extern __shared__ char sm[];
  float* u  = (float*)(sm + FN_U);                    // [8][260]
  float* v  = (float*)(sm + FN_V);
  float* hr = (float*)(sm + FN_HR);                   // [256]

  int b = blockIdx.x >> 5, r0 = (blockIdx.x & 31) * 8;
  int tid = threadIdx.x;

  if (tid < 64) {                                     // h_rt = concat(fh, bh)
    int k = tid * 4;
    f32x4 x = (tid < 32) ? *(const f32x4*)(fh + b * 128 + k)
                         : *(const f32x4*)(bh + b * 128 + k - 128);
    *(f32x4*)(hr + k) = x;
  }
  __syncthreads();
  #pragma unroll
  for (int rep = 0; rep < 2; ++rep) {                 // u = lt*h_rt ; v = lt*att
    int c = rep * 256 + tid;
    int row = c >> 6, c4 = c & 63;
    size_t g = ((size_t)b * 256 + r0 + row) * 256 + c4 * 4;
    f32x4 lv = *(const f32x4*)(lt + g);
    f32x4 hv = *(const f32x4*)(hr + c4 * 4);
    f32x4 av = *(const f32x4*)(attw + g);
    *(f32x4*)(u + row * 260 + c4 * 4) = lv * hv;
    *(f32x4*)(v + row * 260 + c4 * 4) = lv * av;
  }
  __syncthreads();
  int r = tid >> 5, l = tid & 31;
  float af = 0.f, aa = 0.f, am = 0.f;
  #pragma unroll 8
  for (int c4 = 0; c4 < 64; ++c4) {
    f32x4 uu = *(const f32x4*)(u + r * 260 + c4 * 4);
    f32x4 vv = *(const f32x4*)(v + r * 260 + c4 * 4);
    f32x4 w1 = *(const f32x4*)(Wf + l * 256 + c4 * 4);
    f32x4 w2 = *(const f32x4*)(Wa + l * 256 + c4 * 4);
    f32x4 w3 = *(const f32x4*)(Wm + l * 256 + c4 * 4);
    af += uu.x * w1.x + uu.y * w1.y + uu.z * w1.z + uu.w * w1.w;
    aa += vv.x * w2.x + vv.y * w2.y + vv.z * w2.z + vv.w * w2.w;
    am += vv.x * w3.x + vv.y * w3.y + vv.z * w3.z + vv.w * w3.w;
  }
  size_t ob = ((size_t)b * 256 + r0 + r) * 128;
  out[ob + l]      = tanhf(af);
  out[ob + 64 + l] = tanhf(aa);
  out[ob + 96 + l] = tanhf(am);
}

// ---------------- launch ------------------------------------------------------
extern "C" void kernel_launch(void* const* d_in, const int* in_sizes, int n_in,
                              void* d_out, int out_size, void* d_ws, size_t ws_size,
                              hipStream_t stream) {
  const float* lt  = (const float*)d_in[0];
  const float* rt  = (const float*)d_in[5];
  const float* fh  = (const float*)d_in[6];
  const float* bh  = (const float*)d_in[8];
  const float* Wf  = (const float*)d_in[10];
  const float* Wmp = (const float*)d_in[11];
  const float* Wa  = (const float*)d_in[12];
  const float* Wm  = (const float*)d_in[13];
  float* out = (float*)d_out;

  char* ws = (char*)d_ws;
  u16* rt_hi = (u16*)(ws);                      // 4 MB
  u16* rt_lo = (u16*)(ws + (4u << 20));         // 4 MB
  u16* rtT   = (u16*)(ws + (8u << 20));         // 4 MB
  float* att = (float*)(ws + (12u << 20));      // 8 MB
  float* nl_inv = (float*)(ws + (20u << 20));
  float* nr_inv = (float*)(ws + (20u << 20) + 32768);

  (void)hipFuncSetAttribute((const void*)k_att,     hipFuncAttributeMaxDynamicSharedMemorySize, ATT_SM);
  (void)hipFuncSetAttribute((const void*)k_maxpool, hipFuncAttributeMaxDynamicSharedMemorySize, MP_SM);
  (void)hipFuncSetAttribute((const void*)k_finals,  hipFuncAttributeMaxDynamicSharedMemorySize, FN_SM);

  k_prep_lt<<<2048, 256, 0, stream>>>(lt, nl_inv);
  k_prep_rt<<<128, 256, 0, stream>>>(rt, rt_hi, rt_lo, rtT, nr_inv);
  k_att<<<256, 256, ATT_SM, stream>>>(lt, rt_hi, rt_lo, rtT, nl_inv, nr_inv, att);
  k_maxpool<<<2048, 256, MP_SM, stream>>>(lt, rt_hi, Wmp, out);
  k_finals<<<1024, 256, FN_SM, stream>>>(lt, fh, bh, Wf, Wa, Wm, att, out);
}

// Round 12
// 231.311 us; speedup vs baseline: 1.7408x; 1.3342x over previous
//
#include <hip/hip_runtime.h>
#include <hip/hip_bf16.h>
#include <math.h>

// MultiPerspectiveLayer: B=32, TL=TR=D=256, L=32
// out[b][t][0:32]=full, [32:64]=maxpool, [64:96]=attentive, [96:128]=max_attentive

typedef __attribute__((ext_vector_type(4)))  float f32x4;
typedef __attribute__((ext_vector_type(16))) float f32x16;
typedef __attribute__((ext_vector_type(8)))  short s16x8;   // 8 bf16 (4 VGPR) MFMA operand
typedef __attribute__((ext_vector_type(4)))  unsigned short u16x4;
typedef __attribute__((ext_vector_type(8)))  unsigned short u16x8;
typedef unsigned short u16;

#define DEV static __device__ __forceinline__

DEV u16 f2bf(float f) {                       // RNE float->bf16 (no NaN in data)
  unsigned u = __builtin_bit_cast(unsigned, f);
  return (u16)((u + 0x7FFFu + ((u >> 16) & 1u)) >> 16);
}
DEV float bf2f(u16 s) { return __builtin_bit_cast(float, ((unsigned)s) << 16); }
DEV f32x16 zero16() {
  f32x16 a;
  #pragma unroll
  for (int i = 0; i < 16; ++i) a[i] = 0.f;
  return a;
}

// ---------------- prep_lt: nl_inv[b*TL+i] = 1/sqrt(max(sum lt^2, eps)) --------
__global__ __launch_bounds__(256) void k_prep_lt(const float* __restrict__ lt,
                                                 float* __restrict__ nl_inv) {
  int w = threadIdx.x >> 6, lane = threadIdx.x & 63;
  int row = blockIdx.x * 4 + w;                       // 8192 rows
  f32x4 v = *(const f32x4*)(lt + (size_t)row * 256 + lane * 4);
  float s = v.x * v.x + v.y * v.y + v.z * v.z + v.w * v.w;
  #pragma unroll
  for (int m = 32; m >= 1; m >>= 1) s += __shfl_xor(s, m);
  if (lane == 0) nl_inv[row] = 1.0f / sqrtf(fmaxf(s, 1e-6f));
}

// ---------------- prep_rt: rt hi/lo bf16, transposed rtT (hi), nr_inv ---------
__global__ __launch_bounds__(256) void k_prep_rt(const float* __restrict__ rt,
                                                 u16* __restrict__ rt_hi,
                                                 u16* __restrict__ rt_lo,
                                                 u16* __restrict__ rtT,
                                                 float* __restrict__ nr_inv) {
  __shared__ u16 ldsT[256][68];                       // pad 68: conflict-spread transpose writes
  int b = blockIdx.x >> 2, j0 = (blockIdx.x & 3) * 64;
  int tid = threadIdx.x, w = tid >> 6, lane = tid & 63;
  for (int rep = 0; rep < 16; ++rep) {
    int jl = rep * 4 + w, j = j0 + jl;
    size_t base = ((size_t)b * 256 + j) * 256;
    float ss = 0.f;
    #pragma unroll
    for (int k = 0; k < 4; ++k) {
      int d = lane + k * 64;
      float f = rt[base + d];
      ss += f * f;
      u16 h = f2bf(f);
      rt_hi[base + d] = h;
      rt_lo[base + d] = f2bf(f - bf2f(h));
      ldsT[d][jl] = h;
    }
    #pragma unroll
    for (int m = 32; m >= 1; m >>= 1) ss += __shfl_xor(ss, m);
    if (lane == 0) nr_inv[b * 256 + j] = 1.0f / sqrtf(fmaxf(ss, 1e-6f));
  }
  __syncthreads();
  for (int rep = 0; rep < 16; ++rep) {                // write rtT[b][d][j0..j0+63]
    int c = rep * 256 + tid;
    int d = c >> 4, q = c & 15;
    u16x4 v = *(const u16x4*)&ldsT[d][q * 4];
    *(u16x4*)(rtT + ((size_t)b * 256 + d) * 256 + j0 + q * 4) = v;
  }
}

// ---------------- attentive path: scores (split-bf16 3-pass) + PV (2-pass) ----
// block = (b, 32-row i-tile); 4 waves; MFMA 16x16x32.
#define ATT_LTH 0
#define ATT_LTL 16384
#define ATT_RTH 32768
#define ATT_RTL 65536
#define ATT_RTT 98304
#define ATT_PH  131072
#define ATT_PL  135168
#define ATT_NLS 139264
#define ATT_NRS 139392
#define ATT_SM  140416

__global__ __launch_bounds__(256) void k_att(const float* __restrict__ lt,
                                             const u16* __restrict__ rt_hi,
                                             const u16* __restrict__ rt_lo,
                                             const u16* __restrict__ rtT,
                                             const float* __restrict__ nl_inv,
                                             const float* __restrict__ nr_inv,
                                             float* __restrict__ att) {
  extern __shared__ char sm[];
  char* LTH = sm + ATT_LTH;  char* LTL = sm + ATT_LTL;
  char* RTH = sm + ATT_RTH;  char* RTL = sm + ATT_RTL;
  char* RTT = sm + ATT_RTT;
  char* PH  = sm + ATT_PH;   char* PL  = sm + ATT_PL;
  float* nls = (float*)(sm + ATT_NLS);
  float* nrs = (float*)(sm + ATT_NRS);

  int b = blockIdx.x >> 3, i0 = (blockIdx.x & 7) * 32;
  int tid = threadIdx.x, w = tid >> 6, lane = tid & 63;

  // stage lt tile [32][256] -> hi/lo bf16, XOR-swizzled rows
  #pragma unroll
  for (int rep = 0; rep < 8; ++rep) {
    int c = rep * 256 + tid;
    int row = c >> 6, c4 = c & 63;
    f32x4 v = *(const f32x4*)(lt + ((size_t)b * 256 + i0 + row) * 256 + c4 * 4);
    u16x4 h, lo;
    #pragma unroll
    for (int k = 0; k < 4; ++k) { float f = v[k]; h[k] = f2bf(f); lo[k] = f2bf(f - bf2f(h[k])); }
    int off = row * 512 + ((c4 * 8) ^ ((row & 7) << 4));
    *(u16x4*)(LTH + off) = h;
    *(u16x4*)(LTL + off) = lo;
  }
  if (tid < 32) nls[tid] = nl_inv[b * 256 + i0 + tid];
  nrs[tid] = nr_inv[b * 256 + tid];

  int ih = w >> 1;
  f32x4 accv[8];
  #pragma unroll
  for (int i = 0; i < 8; ++i) { accv[i].x = 0; accv[i].y = 0; accv[i].z = 0; accv[i].w = 0; }

  for (int jt = 0; jt < 4; ++jt) {
    int j0 = jt * 64;
    __syncthreads();                                   // protect rt/rtT/P from prev iter readers
    #pragma unroll
    for (int rep = 0; rep < 8; ++rep) {                // rt j-tile [64][256] hi/lo
      int c = rep * 256 + tid;
      int row = c >> 5, s = c & 31;
      size_t g = ((size_t)b * 256 + j0 + row) * 256 + s * 8;
      int off = row * 512 + ((s * 16) ^ ((row & 7) << 4));
      *(u16x8*)(RTH + off) = *(const u16x8*)(rt_hi + g);
      *(u16x8*)(RTL + off) = *(const u16x8*)(rt_lo + g);
    }
    #pragma unroll
    for (int rep = 0; rep < 8; ++rep) {                // rtT tile [256][64] (hi)
      int c = rep * 256 + tid;
      int d = c >> 3, s = c & 7;
      *(u16x8*)(RTT + d * 128 + ((s * 16) ^ ((d & 7) << 4))) =
          *(const u16x8*)(rtT + ((size_t)b * 256 + d) * 256 + j0 + s * 8);
    }
    __syncthreads();

    // QK^T: S[32][64]; wave w does frags (ih, jqs..jqs+1); 3-pass split
    f32x4 S[2];
    #pragma unroll
    for (int t = 0; t < 2; ++t) { S[t].x = 0; S[t].y = 0; S[t].z = 0; S[t].w = 0; }
    int jqs = (w & 1) * 2;
    #pragma unroll
    for (int ks = 0; ks < 8; ++ks) {
      int k2 = (ks * 32 + (lane >> 4) * 8) * 2;
      int ar = ih * 16 + (lane & 15);
      int ab = ar * 512 + (k2 ^ ((ar & 7) << 4));
      s16x8 ah = *(const s16x8*)(LTH + ab);
      s16x8 al = *(const s16x8*)(LTL + ab);
      #pragma unroll
      for (int fj = 0; fj < 2; ++fj) {
        int br = (jqs + fj) * 16 + (lane & 15);
        int bb = br * 512 + (k2 ^ ((br & 7) << 4));
        s16x8 bh = *(const s16x8*)(RTH + bb);
        s16x8 bl = *(const s16x8*)(RTL + bb);
        S[fj] = __builtin_amdgcn_mfma_f32_16x16x32_bf16(ah, bh, S[fj], 0, 0, 0);
        S[fj] = __builtin_amdgcn_mfma_f32_16x16x32_bf16(ah, bl, S[fj], 0, 0, 0);
        S[fj] = __builtin_amdgcn_mfma_f32_16x16x32_bf16(al, bh, S[fj], 0, 0, 0);
      }
    }
    // scale by 1/(nl*nr), split to P_hi/P_lo
    #pragma unroll
    for (int fj = 0; fj < 2; ++fj) {
      #pragma unroll
      for (int r = 0; r < 4; ++r) {
        int i = ih * 16 + (lane >> 4) * 4 + r;
        int j = (jqs + fj) * 16 + (lane & 15);
        float v = S[fj][r] * nls[i] * nrs[j0 + j];
        u16 h = f2bf(v), l2 = f2bf(v - bf2f(h));
        int pb = i * 128 + ((j * 2) ^ ((i & 7) << 4));
        *(u16*)(PH + pb) = h;
        *(u16*)(PL + pb) = l2;
      }
    }
    __syncthreads();

    // PV: att[32][256] += P @ rt ; B-operand from rtT (contiguous j); 2-pass split on P
    int db = (w & 1) * 128;
    #pragma unroll
    for (int ks = 0; ks < 2; ++ks) {
      int k2 = (ks * 32 + (lane >> 4) * 8) * 2;
      int pr = ih * 16 + (lane & 15);
      int pb = pr * 128 + (k2 ^ ((pr & 7) << 4));
      s16x8 ph = *(const s16x8*)(PH + pb);
      s16x8 pl = *(const s16x8*)(PL + pb);
      #pragma unroll
      for (int dq = 0; dq < 8; ++dq) {
        int dr = db + dq * 16 + (lane & 15);
        int bb = dr * 128 + (k2 ^ ((dr & 7) << 4));
        s16x8 bv = *(const s16x8*)(RTT + bb);
        accv[dq] = __builtin_amdgcn_mfma_f32_16x16x32_bf16(ph, bv, accv[dq], 0, 0, 0);
        accv[dq] = __builtin_amdgcn_mfma_f32_16x16x32_bf16(pl, bv, accv[dq], 0, 0, 0);
      }
    }
  }
  // epilogue: write att fp32
  #pragma unroll
  for (int dq = 0; dq < 8; ++dq) {
    #pragma unroll
    for (int r = 0; r < 4; ++r) {
      int i = i0 + ih * 16 + (lane >> 4) * 4 + r;
      int d = (w & 1) * 128 + dq * 16 + (lane & 15);
      att[((size_t)b * 256 + i) * 256 + d] = accv[dq][r];
    }
  }
}

// ---------------- maxpool matching v4: A-frags in regs, B [128j][256k] LDS ----
// block = (b, l, i0 in {0,128}); 4 waves, wave w owns 32 i-rows (full K in fa[16],
// 64 VGPR) x 128 j per stage (acc[4] f32x16, 64 VGPR). A never touches LDS; B
// staged twice (j-halves), full-K per stage so rowmax follows immediately.
// LDS: B 64 KB + red 1 KB = 65 KB -> 2 blocks/CU. 4 barriers/block.
#define MP_B   0
#define MP_RED 65536
#define MP_SM  66560

__global__ __launch_bounds__(256, 2) void k_maxpool(const float* __restrict__ lt,
                                                    const u16* __restrict__ rt_hi,
                                                    const float* __restrict__ Wmp,
                                                    float* __restrict__ out) {
  extern __shared__ char sm[];
  char* Bm = sm + MP_B;
  float* red = (float*)(sm + MP_RED);                 // [2 jh][128 i]

  int b = blockIdx.x >> 6, rem = blockIdx.x & 63;
  int l = rem >> 1, i0 = (rem & 1) * 128;
  int tid = threadIdx.x, lane = tid & 63, w = tid >> 6;

  // fa: row = i0 + w*32 + (lane&31), cols ks*16 + (lane>>5)*8 + 0..7 (full K)
  s16x8 fa[16];
  {
    int kc0 = (lane >> 5) * 8;
    int arow = i0 + w * 32 + (lane & 31);
    const float* asrc = lt + ((size_t)b * 256 + arow) * 256 + kc0;
    const float* wsrc = Wmp + l * 256 + kc0;
    #pragma unroll
    for (int ks = 0; ks < 16; ++ks) {
      f32x4 v0 = *(const f32x4*)(asrc + ks * 16);
      f32x4 v1 = *(const f32x4*)(asrc + ks * 16 + 4);
      f32x4 w0 = *(const f32x4*)(wsrc + ks * 16);
      f32x4 w1 = *(const f32x4*)(wsrc + ks * 16 + 4);
      s16x8 a;
      a[0] = (short)f2bf(v0.x * w0.x); a[1] = (short)f2bf(v0.y * w0.y);
      a[2] = (short)f2bf(v0.z * w0.z); a[3] = (short)f2bf(v0.w * w0.w);
      a[4] = (short)f2bf(v1.x * w1.x); a[5] = (short)f2bf(v1.y * w1.y);
      a[6] = (short)f2bf(v1.z * w1.z); a[7] = (short)f2bf(v1.w * w1.w);
      fa[ks] = a;
    }
  }

  for (int jh = 0; jh < 2; ++jh) {
    if (jh) __syncthreads();                          // all waves done reading B(jh=0)
    // stage B = rt_hi rows jh*128..+127, [128 j][256 k] bf16 swizzled
    #pragma unroll
    for (int rep = 0; rep < 16; ++rep) {
      int row = rep * 8 + (tid >> 5);
      int s = tid & 31;
      *(u16x8*)(Bm + row * 512 + ((s * 16) ^ ((row & 7) << 4))) =
          *(const u16x8*)(rt_hi + ((size_t)b * 256 + jh * 128 + row) * 256 + s * 8);
    }
    __syncthreads();

    f32x16 a0 = zero16(), a1 = zero16(), a2 = zero16(), a3 = zero16();
    #pragma unroll
    for (int ks = 0; ks < 16; ++ks) {
      int k2 = (ks * 16 + (lane >> 5) * 8) * 2;
      int r0 = (lane & 31),      r1 = r0 + 32;
      int r2 = r0 + 64,          r3 = r0 + 96;
      s16x8 fb0 = *(const s16x8*)(Bm + r0 * 512 + (k2 ^ ((r0 & 7) << 4)));
      s16x8 fb1 = *(const s16x8*)(Bm + r1 * 512 + (k2 ^ ((r1 & 7) << 4)));
      s16x8 fb2 = *(const s16x8*)(Bm + r2 * 512 + (k2 ^ ((r2 & 7) << 4)));
      s16x8 fb3 = *(const s16x8*)(Bm + r3 * 512 + (k2 ^ ((r3 & 7) << 4)));
      a0 = __builtin_amdgcn_mfma_f32_32x32x16_bf16(fa[ks], fb0, a0, 0, 0, 0);
      a1 = __builtin_amdgcn_mfma_f32_32x32x16_bf16(fa[ks], fb1, a1, 0, 0, 0);
      a2 = __builtin_amdgcn_mfma_f32_32x32x16_bf16(fa[ks], fb2, a2, 0, 0, 0);
      a3 = __builtin_amdgcn_mfma_f32_32x32x16_bf16(fa[ks], fb3, a3, 0, 0, 0);
    }
    // rowmax over the 128 j of this stage: frags, then 32 lanes (j cols)
    #pragma unroll
    for (int r = 0; r < 16; ++r) {
      float v = fmaxf(fmaxf(a0[r], a1[r]), fmaxf(a2[r], a3[r]));
      #pragma unroll
      for (int m = 16; m >= 1; m >>= 1) v = fmaxf(v, __shfl_xor(v, m));
      if ((lane & 31) == 0)
        red[jh * 128 + w * 32 + (r & 3) + 8 * (r >> 2) + 4 * (lane >> 5)] = v;
    }
  }
  __syncthreads();
  if (tid < 128) {
    float m = fmaxf(red[tid], red[128 + tid]);
    out[((size_t)b * 256 + i0 + tid) * 128 + 32 + l] = tanhf(m);
  }
}

// ---------------- finals: full / attentive / max_attentive (exact fp32) ------
// W from global with BROADCAST-friendly mapping: l = tid>>3 (8 lanes share one
// W row -> same-address broadcast), r = tid&7. u/v in LDS (pad 260 -> 4-bank
// row rotation, conflict-free). 17.4 KB LDS.
#define FN_U  0
#define FN_V  8320
#define FN_HR 16640
#define FN_SM 17664

__global__ __launch_bounds__(256) void k_finals(const float* __restrict__ lt,
                                                const float* __restrict__ fh,
                                                const float* __restrict__ bh,
                                                const float* __restrict__ Wf,
                                                const float* __restrict__ Wa,
                                                const float* __restrict__ Wm,
                                                const float* __restrict__ attw,
                                                float* __restrict__ out) {
  extern __shared__ char sm[];
  float* u  = (float*)(sm + FN_U);                    // [8][260]
  float* v  = (float*)(sm + FN_V);
  float* hr = (float*)(sm + FN_HR);                   // [256]

  int b = blockIdx.x >> 5, r0 = (blockIdx.x & 31) * 8;
  int tid = threadIdx.x;

  if (tid < 64) {                                     // h_rt = concat(fh, bh)
    int k = tid * 4;
    f32x4 x = (tid < 32) ? *(const f32x4*)(fh + b * 128 + k)
                         : *(const f32x4*)(bh + b * 128 + k - 128);
    *(f32x4*)(hr + k) = x;
  }
  __syncthreads();
  #pragma unroll
  for (int rep = 0; rep < 2; ++rep) {                 // u = lt*h_rt ; v = lt*att
    int c = rep * 256 + tid;
    int row = c >> 6, c4 = c & 63;
    size_t g = ((size_t)b * 256 + r0 + row) * 256 + c4 * 4;
    f32x4 lv = *(const f32x4*)(lt + g);
    f32x4 hv = *(const f32x4*)(hr + c4 * 4);
    f32x4 av = *(const f32x4*)(attw + g);
    *(f32x4*)(u + row * 260 + c4 * 4) = lv * hv;
    *(f32x4*)(v + row * 260 + c4 * 4) = lv * av;
  }
  __syncthreads();
  int l = tid >> 3, r = tid & 7;                      // 8 lanes share one W row
  float af = 0.f, aa = 0.f, am = 0.f;
  #pragma unroll 8
  for (int c4 = 0; c4 < 64; ++c4) {
    f32x4 uu = *(const f32x4*)(u + r * 260 + c4 * 4);
    f32x4 vv = *(const f32x4*)(v + r * 260 + c4 * 4);
    f32x4 w1 = *(const f32x4*)(Wf + l * 256 + c4 * 4);
    f32x4 w2 = *(const f32x4*)(Wa + l * 256 + c4 * 4);
    f32x4 w3 = *(const f32x4*)(Wm + l * 256 + c4 * 4);
    af += uu.x * w1.x + uu.y * w1.y + uu.z * w1.z + uu.w * w1.w;
    aa += vv.x * w2.x + vv.y * w2.y + vv.z * w2.z + vv.w * w2.w;
    am += vv.x * w3.x + vv.y * w3.y + vv.z * w3.z + vv.w * w3.w;
  }
  size_t ob = ((size_t)b * 256 + r0 + r) * 128;
  out[ob + l]      = tanhf(af);
  out[ob + 64 + l] = tanhf(aa);
  out[ob + 96 + l] = tanhf(am);
}

// ---------------- launch ------------------------------------------------------
extern "C" void kernel_launch(void* const* d_in, const int* in_sizes, int n_in,
                              void* d_out, int out_size, void* d_ws, size_t ws_size,
                              hipStream_t stream) {
  const float* lt  = (const float*)d_in[0];
  const float* rt  = (const float*)d_in[5];
  const float* fh  = (const float*)d_in[6];
  const float* bh  = (const float*)d_in[8];
  const float* Wf  = (const float*)d_in[10];
  const float* Wmp = (const float*)d_in[11];
  const float* Wa  = (const float*)d_in[12];
  const float* Wm  = (const float*)d_in[13];
  float* out = (float*)d_out;

  char* ws = (char*)d_ws;
  u16* rt_hi = (u16*)(ws);                      // 4 MB
  u16* rt_lo = (u16*)(ws + (4u << 20));         // 4 MB
  u16* rtT   = (u16*)(ws + (8u << 20));         // 4 MB
  float* att = (float*)(ws + (12u << 20));      // 8 MB
  float* nl_inv = (float*)(ws + (20u << 20));
  float* nr_inv = (float*)(ws + (20u << 20) + 32768);

  (void)hipFuncSetAttribute((const void*)k_att,     hipFuncAttributeMaxDynamicSharedMemorySize, ATT_SM);
  (void)hipFuncSetAttribute((const void*)k_maxpool, hipFuncAttributeMaxDynamicSharedMemorySize, MP_SM);
  (void)hipFuncSetAttribute((const void*)k_finals,  hipFuncAttributeMaxDynamicSharedMemorySize, FN_SM);

  k_prep_lt<<<2048, 256, 0, stream>>>(lt, nl_inv);
  k_prep_rt<<<128, 256, 0, stream>>>(rt, rt_hi, rt_lo, rtT, nr_inv);
  k_att<<<256, 256, ATT_SM, stream>>>(lt, rt_hi, rt_lo, rtT, nl_inv, nr_inv, att);
  k_maxpool<<<2048, 256, MP_SM, stream>>>(lt, rt_hi, Wmp, out);
  k_finals<<<1024, 256, FN_SM, stream>>>(lt, fh, bh, Wf, Wa, Wm, att, out);
}